// Round 1
// 209.989 us; speedup vs baseline: 1.0691x; 1.0691x over previous
//
#include <hip/hip_runtime.h>

typedef __attribute__((ext_vector_type(8))) __bf16 bf16x8;
typedef __attribute__((ext_vector_type(8))) unsigned short ushort8v;
typedef __attribute__((ext_vector_type(4))) float f32x4;

__device__ __forceinline__ unsigned short f2bf(float f) {
  return __builtin_bit_cast(unsigned short, (__bf16)f);
}

// Swizzled byte offsets (XOR row-bits into the 16B-slot index -> no bank conflicts, G4)
__device__ __forceinline__ int qoff(int row, int colb) {  // 256B rows (A/Q/K[64][128] bf16)
  return row * 256 + (colb ^ ((row & 7) << 4));
}
__device__ __forceinline__ int toff(int row, int colb) {  // 128B rows (VT[128][64], S'[64][64] bf16)
  return row * 128 + (colb ^ ((row & 7) << 4));
}

__global__ void prep_w(const float* __restrict__ Wq, const float* __restrict__ Wk,
                       const float* __restrict__ Wv, unsigned short* __restrict__ ws) {
  int i = blockIdx.x * 256 + threadIdx.x;
  if (i >= 3 * 16384) return;
  const float* s = (i < 16384) ? Wq : (i < 32768 ? Wk : Wv);
  ws[i] = f2bf(s[i & 16383]);
}

// One short-lived block (8 waves, 512 thr) per batch row.
// LDS cut 66K -> 49.7K for 3 blocks/CU (24 waves/CU): V projection is DEFERRED to
// after the S-phase barrier, so VT overlays sQ (Q dead) and S' overlays sK (K dead).
// V weights are loaded AFTER the Q/K GEMM (latency drained free by B3's vmcnt(0)),
// keeping peak VGPR pressure <= 64 so 3 blocks can actually co-reside.
__global__ __launch_bounds__(512, 8) void fused_attn(
    const float* __restrict__ x, const unsigned short* __restrict__ wsW,
    const float* __restrict__ bq, const float* __restrict__ bk, const float* __restrict__ bv,
    const float* __restrict__ ln_w, const float* __restrict__ ln_b,
    float* __restrict__ out) {
  __shared__ __align__(16) unsigned char smem[49728];
  unsigned char* sA = smem;          // xnorm A[64][128] bf16 (qoff); live until V-GEMM
  unsigned char* sQ = smem + 16384;  // Q[64][128] bf16 (qoff); VT[128][64] (toff) after B3b
  unsigned char* sK = smem + 32768;  // K[64][128] bf16 (qoff); S'[64][64] (toff) after B3b
  float* redS  = (float*)(smem + 49152);        // 16 floats LN scratch
  float* pPart = (float*)(smem + 49152 + 64);   // [8][16] S rowsum partials

  const int tid = threadIdx.x;
  const int lane = tid & 63;
  const int w = tid >> 6;            // wave 0..7
  const int l15 = lane & 15;
  const int l4 = lane >> 4;          // 0..3
  const size_t bofs = (size_t)blockIdx.x * 8192;

  // ---- Q,K weights -> VGPRs (issued FIRST; latency covered by x-load + LN) ----
  // wave w owns output cols [16w, 16w+16) of Q, K (and later V).
  bf16x8 wf[2][4];
  const int col = (w << 4) + l15;
#pragma unroll
  for (int m = 0; m < 2; ++m) {
    const unsigned short* wp = wsW + m * 16384 + col * 128 + (l4 << 3);
#pragma unroll
    for (int kk = 0; kk < 4; ++kk)
      wf[m][kk] = *(const bf16x8*)(wp + kk * 32);
  }
  const float biasQ = bq[col], biasK = bk[col], biasV = bv[col];

  // ---- Phase 1: x load (16 elems/thread) + LayerNorm ----
  // thread -> row_x = tid>>3 (0..63), cols [c0, c0+16), c0 = (tid&7)*16
  const int row_x = tid >> 3;
  const int c0 = (tid & 7) << 4;
  float xv[16];
  float s1 = 0.f, s2 = 0.f;
  {
    const float* xp = x + bofs + (size_t)row_x * 128 + c0;
#pragma unroll
    for (int i = 0; i < 4; ++i) {
      float4 a = *(const float4*)(xp + i * 4);
      xv[i*4+0]=a.x; xv[i*4+1]=a.y; xv[i*4+2]=a.z; xv[i*4+3]=a.w;
      s1 += a.x+a.y+a.z+a.w;
      s2 += a.x*a.x+a.y*a.y+a.z*a.z+a.w*a.w;
    }
  }
#pragma unroll
  for (int off = 32; off > 0; off >>= 1) {
    s1 += __shfl_xor(s1, off, 64);
    s2 += __shfl_xor(s2, off, 64);
  }
  if (lane == 0) { redS[w] = s1; redS[8 + w] = s2; }
  __syncthreads();  // B1
  float t1 = 0.f, t2 = 0.f;
#pragma unroll
  for (int p = 0; p < 8; ++p) { t1 += redS[p]; t2 += redS[8 + p]; }
  const float mu = t1 * (1.f / 8192.f);
  const float rstd = rsqrtf(t2 * (1.f / 8192.f) - mu * mu + 1e-5f);

  // ---- xnorm -> bf16 A in LDS (qoff layout; two 16B chunks per thread) ----
  {
    const float* pw = ln_w + row_x * 128 + c0;
    const float* pb = ln_b + row_x * 128 + c0;
#pragma unroll
    for (int h = 0; h < 2; ++h) {
      ushort8v t;
#pragma unroll
      for (int j = 0; j < 8; ++j) {
        float wr = pw[h * 8 + j], br = pb[h * 8 + j];
        t[j] = f2bf((xv[h*8+j] - mu) * rstd * wr + br);
      }
      *(ushort8v*)(sA + qoff(row_x, (c0 << 1) + h * 16)) = t;
    }
  }
  __syncthreads();  // B2: A visible

  // ---- GEMM1 (col-split): 4 m-tiles x wave's 1 col-tile; Q/K from reg-weights ----
#pragma unroll
  for (int mt = 0; mt < 4; ++mt) {
    bf16x8 aq[4];
#pragma unroll
    for (int kk = 0; kk < 4; ++kk)
      aq[kk] = *(const bf16x8*)(sA + qoff(mt * 16 + l15, kk * 64 + (l4 << 4)));
    const int i0m = mt * 16 + (l4 << 2);
    f32x4 aQ = {0,0,0,0}, aK = {0,0,0,0};
#pragma unroll
    for (int kk = 0; kk < 4; ++kk) {
      aQ = __builtin_amdgcn_mfma_f32_16x16x32_bf16(aq[kk], wf[0][kk], aQ, 0, 0, 0);
      aK = __builtin_amdgcn_mfma_f32_16x16x32_bf16(aq[kk], wf[1][kk], aK, 0, 0, 0);
    }
#pragma unroll
    for (int rr = 0; rr < 4; ++rr) {
      float zq = aQ[rr] + biasQ; zq = zq > 0.f ? zq + 1.f : __expf(zq);
      *(unsigned short*)(sQ + qoff(i0m + rr, col * 2)) = f2bf(zq);
      float zk = aK[rr] + biasK; zk = zk > 0.f ? zk + 1.f : __expf(zk);
      *(unsigned short*)(sK + qoff(i0m + rr, col * 2)) = f2bf(zk);
    }
  }
  // V weights -> VGPRs now (Q/K weights die above; loads drain for free at B3's vmcnt(0))
  bf16x8 wfV[4];
  {
    const unsigned short* wp = wsW + 2 * 16384 + col * 128 + (l4 << 3);
#pragma unroll
    for (int kk = 0; kk < 4; ++kk)
      wfV[kk] = *(const bf16x8*)(wp + kk * 32);
  }
  __syncthreads();  // B3: Q,K visible

  // ---- S = Q K^T: wave (st,half) -> S rows [16st,16st+16) x cols [32half,32half+32) ----
  const int st = w >> 1;          // S row-tile 0..3
  const int half = w & 1;         // col half
  const int i0s = st * 16 + (l4 << 2);
  f32x4 accS[2];
  {
    bf16x8 aq[4];
#pragma unroll
    for (int kk = 0; kk < 4; ++kk)
      aq[kk] = *(const bf16x8*)(sQ + qoff(st * 16 + l15, kk * 64 + (l4 << 4)));
#pragma unroll
    for (int nt = 0; nt < 2; ++nt) {
      const int ntg = half * 2 + nt;
      f32x4 acc = {0,0,0,0};
#pragma unroll
      for (int kk = 0; kk < 4; ++kk) {
        bf16x8 bk_ = *(const bf16x8*)(sK + qoff(ntg * 16 + l15, kk * 64 + (l4 << 4)));
        acc = __builtin_amdgcn_mfma_f32_16x16x32_bf16(aq[kk], bk_, acc, 0, 0, 0);
      }
      accS[nt] = acc;
    }
    float p[4];
#pragma unroll
    for (int rr = 0; rr < 4; ++rr) p[rr] = accS[0][rr] + accS[1][rr];
#pragma unroll
    for (int off = 1; off < 16; off <<= 1) {
#pragma unroll
      for (int rr = 0; rr < 4; ++rr) p[rr] += __shfl_xor(p[rr], off, 64);
    }
    if (l15 == 0) {
#pragma unroll
      for (int rr = 0; rr < 4; ++rr)
        pPart[w * 16 + (l4 << 2) + rr] = p[rr];  // partial rowsum over this half's 32 cols
    }
  }
  __syncthreads();  // B3b: partials visible; all sQ/sK reads drained -> safe to overlay

  // ---- V = A @ Wv^T -> VT overlays sQ (toff); wave w owns V cols [16w,16w+16) ----
#pragma unroll
  for (int mt = 0; mt < 4; ++mt) {
    bf16x8 aq[4];
#pragma unroll
    for (int kk = 0; kk < 4; ++kk)
      aq[kk] = *(const bf16x8*)(sA + qoff(mt * 16 + l15, kk * 64 + (l4 << 4)));
    f32x4 aV = {0,0,0,0};
#pragma unroll
    for (int kk = 0; kk < 4; ++kk)
      aV = __builtin_amdgcn_mfma_f32_16x16x32_bf16(aq[kk], wfV[kk], aV, 0, 0, 0);
    const int i0m = mt * 16 + (l4 << 2);
    ushort4 pk;
    pk.x = f2bf(aV[0] + biasV); pk.y = f2bf(aV[1] + biasV);
    pk.z = f2bf(aV[2] + biasV); pk.w = f2bf(aV[3] + biasV);
    *(ushort4*)(sQ + toff(col, i0m * 2)) = pk;
  }
  // ---- combine rowsum halves -> nv; S' (norm-folded) overlays sK (toff) ----
  {
    float nv[4];
#pragma unroll
    for (int rr = 0; rr < 4; ++rr) {
      const int r = (l4 << 2) + rr;
      nv[rr] = 1.f / (pPart[(st * 2) * 16 + r] + pPart[(st * 2 + 1) * 16 + r] + 1e-7f);
    }
#pragma unroll
    for (int nt = 0; nt < 2; ++nt) {
      const int ntg = half * 2 + nt;
#pragma unroll
      for (int rr = 0; rr < 4; ++rr)
        *(unsigned short*)(sK + toff(i0s + rr, (ntg * 16 + l15) * 2)) = f2bf(accS[nt][rr] * nv[rr]);
    }
  }
  __syncthreads();  // B4: VT, S' visible

  // ---- P^T[m][l] = sum_i VT[m][i] S'[l][i]; wave w -> m-rows [16w,16w+16) ----
  {
    bf16x8 av[2];
#pragma unroll
    for (int kk = 0; kk < 2; ++kk)
      av[kk] = *(const bf16x8*)(sQ + toff((w << 4) + l15, kk * 64 + (l4 << 4)));
#pragma unroll
    for (int nt = 0; nt < 4; ++nt) {
      bf16x8 bs0 = *(const bf16x8*)(sK + toff(nt * 16 + l15, (l4 << 4)));
      bf16x8 bs1 = *(const bf16x8*)(sK + toff(nt * 16 + l15, 64 + (l4 << 4)));
      f32x4 acc = {0,0,0,0};
      acc = __builtin_amdgcn_mfma_f32_16x16x32_bf16(av[0], bs0, acc, 0, 0, 0);
      acc = __builtin_amdgcn_mfma_f32_16x16x32_bf16(av[1], bs1, acc, 0, 0, 0);
      const int l = nt * 16 + l15;
      const int mb = (w << 4) + (l4 << 2);
      const size_t idx = bofs + (size_t)l * 128 + mb;
      f32x4 xr = *(const f32x4*)(x + idx);  // LLC-hot residual re-read
      f32x4 o;
      o[0] = acc[0] + xr[0]; o[1] = acc[1] + xr[1];
      o[2] = acc[2] + xr[2]; o[3] = acc[3] + xr[3];
      __builtin_nontemporal_store(o, (f32x4*)(out + idx));  // out never re-read: keep LLC for x
    }
  }
}

extern "C" void kernel_launch(void* const* d_in, const int* in_sizes, int n_in,
                              void* d_out, int out_size, void* d_ws, size_t ws_size,
                              hipStream_t stream) {
  const float* x   = (const float*)d_in[0];
  const float* Wq  = (const float*)d_in[1];
  const float* bq  = (const float*)d_in[2];
  const float* Wk  = (const float*)d_in[3];
  const float* bk  = (const float*)d_in[4];
  const float* Wv  = (const float*)d_in[5];
  const float* bv  = (const float*)d_in[6];
  const float* lnw = (const float*)d_in[7];
  const float* lnb = (const float*)d_in[8];
  unsigned short* ws = (unsigned short*)d_ws;  // 96 KB bf16 weights
  float* out = (float*)d_out;

  prep_w<<<192, 256, 0, stream>>>(Wq, Wk, Wv, ws);
  fused_attn<<<8192, 512, 0, stream>>>(x, ws, bq, bk, bv, lnw, lnb, out);
}